// Round 3
// baseline (16321.251 us; speedup 1.0000x reference)
//
#include <hip/hip_runtime.h>
#include <math.h>

#define B_SZ 1024
#define T_SZ 512
#define C_CH 65
#define HID 160
#define G3  480   // 3*HID
#define OUTD 32

// ---------------- phase 0: zero any-flags ----------------
__global__ void k_zero(unsigned* __restrict__ anyv) {
  int i = blockIdx.x * blockDim.x + threadIdx.x;
  if (i < T_SZ) anyv[i] = 0u;
}

// ---------------- phase 1: obs[b][t] + any_obs[t] ----------------
__global__ __launch_bounds__(256) void k_obs(const float* __restrict__ X,
                                             unsigned char* __restrict__ obs,
                                             unsigned* __restrict__ anyv) {
  const int b = blockIdx.x;
  const float* Xb = X + (size_t)b * T_SZ * C_CH;
  for (int t = threadIdx.x; t < T_SZ; t += blockDim.x) {
    const float* cur = Xb + t * C_CH;
    const float* prv = cur - C_CH;
    float m = -1e30f;
    if (t == 0) {
      #pragma unroll
      for (int c = 1; c <= 32; ++c) m = fmaxf(m, cur[c]);
    } else {
      #pragma unroll
      for (int c = 1; c <= 32; ++c) m = fmaxf(m, cur[c] - prv[c]);
    }
    unsigned char o = (m > 0.5f) ? (unsigned char)1 : (unsigned char)0;
    obs[(size_t)b * T_SZ + t] = o;
    if (o) atomicOr(&anyv[t], 1u);
  }
}

__device__ __forceinline__ float sigm_f(float v) {
  return 1.f / (1.f + __expf(-v));
}
__device__ __forceinline__ float tanh_f(float v) {
  float a = fabsf(v);
  float e = __expf(-2.f * a);
  float m = (1.f - e) / (1.f + e);
  return copysignf(m, v);
}

// ---------------- phase 2: recurrence, one block (1024 thr) per element ----
// Row split: thread j (j<480) owns wih[j][0:32) + whh[j][0:64)   (96 w)
//            thread 512+j     owns whh[j][64:160)                (96 w)
// NOTE: __launch_bounds__(1024) with no second arg -> VGPR cap 128 (the
// 16-wave block needs 4 waves/SIMD resident). Round-2's (1024,4) drove the
// cap to 64 and spilled all weights to scratch (34.6 GB HBM fetch).
__global__ __launch_bounds__(1024) void k_scan(
    const float* __restrict__ times, const float* __restrict__ X,
    const int* __restrict__ fidx,
    const float* __restrict__ w_ih, const float* __restrict__ w_hh,
    const float* __restrict__ b_ih, const float* __restrict__ b_hh,
    const float* __restrict__ lin_w, const float* __restrict__ lin_b,
    const unsigned char* __restrict__ obs, const unsigned* __restrict__ anyv,
    float* __restrict__ out)
{
  const int b = blockIdx.x;
  const int tid = threadIdx.x;
  const int fi = fidx[b];
  const float* Xb = X + (size_t)b * T_SZ * C_CH;

  __shared__ __align__(16) float hf[HID];      // hidden state
  __shared__ float2 plo[G3];                   // (gi_partial, gh_lo_partial)
  __shared__ float  phi[G3];                   // gh_hi_partial
  __shared__ float  times_lds[T_SZ];
  __shared__ __align__(16) float xs[2][32];    // dbuf x-piece (ch 33..64)
  __shared__ float  xd0f[2];                   // channel-0 (time delta chan)
  __shared__ int    flagA[2], flagO[2];

  if (tid < T_SZ) times_lds[tid] = times[tid];
  if (tid < HID)  hf[tid] = 0.f;

  const bool isLo = (tid < G3);
  const bool isHi = (tid >= 512 && tid < 512 + G3);
  const int  row  = isLo ? tid : (tid - 512);

  float4 w4[24];                               // 96 weight floats in VGPRs
  float bi = 0.f, bhlo = 0.f;
  if (isLo) {
    const float4* wi = (const float4*)(w_ih + row * 32);
    #pragma unroll
    for (int q = 0; q < 8; ++q) w4[q] = wi[q];
    const float4* wh = (const float4*)(w_hh + (size_t)row * HID);
    #pragma unroll
    for (int q = 0; q < 16; ++q) w4[8 + q] = wh[q];
    bi = b_ih[row];
    bhlo = b_hh[row];
  } else if (isHi) {
    const float4* wh = (const float4*)(w_hh + (size_t)row * HID + 64);
    #pragma unroll
    for (int q = 0; q < 24; ++q) w4[q] = wh[q];
  }

  // stage step 0 into parity 0
  if (tid < 32)       xs[0][tid] = Xb[33 + tid];
  else if (tid == 32) xd0f[0] = Xb[0];
  else if (tid == 33) flagA[0] = (int)anyv[0];
  else if (tid == 34) flagO[0] = (int)obs[(size_t)b * T_SZ];
  float dt = 0.f;
  __syncthreads();

  const float4* h4c = (const float4*)hf;

  for (int t = 0; t <= fi; ++t) {
    const int p = t & 1;

    // issue prefetch of step t+1 early (hides under the matvec)
    float vnext = 0.f; int fnext = 0;
    const int tn = (t < fi) ? (t + 1) : fi;
    if (tid < 32)       vnext = Xb[tn * C_CH + 33 + tid];
    else if (tid == 32) vnext = Xb[tn * C_CH];
    else if (tid == 33) fnext = (int)anyv[tn];
    else if (tid == 34) fnext = (int)obs[(size_t)b * T_SZ + tn];

    const int fa = flagA[p];
    const int fo = flagO[p];

    if (fa) {
      if (fo) {
        // ---- full GRU step ----
        if (isLo) {
          const float4* xp4 = (const float4*)xs[p];
          float4 xv = xp4[0];
          float a0 = fmaf(w4[0].x, xv.x + dt, bi);
          float a1 = w4[0].y * xv.y;
          float a2 = w4[0].z * xv.z;
          float a3 = w4[0].w * xv.w;
          #pragma unroll
          for (int q = 1; q < 8; ++q) {
            float4 v = xp4[q];
            a0 = fmaf(w4[q].x, v.x, a0);
            a1 = fmaf(w4[q].y, v.y, a1);
            a2 = fmaf(w4[q].z, v.z, a2);
            a3 = fmaf(w4[q].w, v.w, a3);
          }
          float g0 = bhlo, g1 = 0.f, g2 = 0.f, g3 = 0.f;
          #pragma unroll
          for (int q = 0; q < 16; ++q) {
            float4 hv = h4c[q];
            g0 = fmaf(w4[8 + q].x, hv.x, g0);
            g1 = fmaf(w4[8 + q].y, hv.y, g1);
            g2 = fmaf(w4[8 + q].z, hv.z, g2);
            g3 = fmaf(w4[8 + q].w, hv.w, g3);
          }
          plo[row] = make_float2((a0 + a1) + (a2 + a3), (g0 + g1) + (g2 + g3));
        } else if (isHi) {
          float g0 = 0.f, g1 = 0.f, g2 = 0.f, g3 = 0.f;
          #pragma unroll
          for (int q = 0; q < 24; ++q) {
            float4 hv = h4c[16 + q];
            g0 = fmaf(w4[q].x, hv.x, g0);
            g1 = fmaf(w4[q].y, hv.y, g1);
            g2 = fmaf(w4[q].z, hv.z, g2);
            g3 = fmaf(w4[q].w, hv.w, g3);
          }
          phi[row] = (g0 + g1) + (g2 + g3);
        }
        __syncthreads();   // partials visible; all h reads done
        if (tid < HID) {
          float2 pr = plo[tid];            float hr = phi[tid];
          float2 pz = plo[HID + tid];      float hz = phi[HID + tid];
          float2 pn = plo[2 * HID + tid];  float hn = phi[2 * HID + tid];
          float r = sigm_f(pr.x + pr.y + hr);
          float z = sigm_f(pz.x + pz.y + hz);
          float n = tanh_f(fmaf(r, pn.y + hn, pn.x));
          float ho = hf[tid];
          hf[tid] = fmaf(z, ho - n, n);    // (1-z)*n + z*h
        }
      } else {
        // dt-only step (block-uniform, redundantly computed)
        dt += xd0f[p] - times_lds[(t == 0) ? 0 : (t - 1)];
      }
    }
    // publish prefetched step t+1, then barrier
    if (tid < 32)       xs[p ^ 1][tid] = vnext;
    else if (tid == 32) xd0f[p ^ 1] = vnext;
    else if (tid == 33) flagA[p ^ 1] = fnext;
    else if (tid == 34) flagO[p ^ 1] = fnext;
    __syncthreads();
  }

  // final linear: out = lin_w @ h + lin_b
  if (tid < OUTD) {
    const float* lw = lin_w + tid * HID;
    float acc = lin_b[tid];
    #pragma unroll
    for (int k = 0; k < HID; ++k) acc = fmaf(lw[k], hf[k], acc);
    out[(size_t)b * OUTD + tid] = acc;
  }
}

extern "C" void kernel_launch(void* const* d_in, const int* in_sizes, int n_in,
                              void* d_out, int out_size, void* d_ws, size_t ws_size,
                              hipStream_t stream) {
  const float* times = (const float*)d_in[0];
  const float* X     = (const float*)d_in[1];
  const int*   fidx  = (const int*)d_in[2];
  const float* w_ih  = (const float*)d_in[3];
  const float* w_hh  = (const float*)d_in[4];
  const float* b_ih  = (const float*)d_in[5];
  const float* b_hh  = (const float*)d_in[6];
  const float* lin_w = (const float*)d_in[7];
  const float* lin_b = (const float*)d_in[8];
  float* outp = (float*)d_out;

  unsigned char* obs = (unsigned char*)d_ws;
  unsigned* anyv = (unsigned*)((char*)d_ws + (size_t)B_SZ * T_SZ);

  k_zero<<<1, 512, 0, stream>>>(anyv);
  k_obs<<<B_SZ, 256, 0, stream>>>(X, obs, anyv);
  k_scan<<<B_SZ, 1024, 0, stream>>>(times, X, fidx, w_ih, w_hh, b_ih, b_hh,
                                    lin_w, lin_b, obs, anyv, outp);
}

// Round 4
// 1459.413 us; speedup vs baseline: 11.1834x; 11.1834x over previous
//
#include <hip/hip_runtime.h>
#include <math.h>

#define B_SZ 1024
#define T_SZ 512
#define C_CH 65
#define HID  160
#define OUTD 32
#define M_ELEM 8
#define NBLK 128          // B_SZ / M_ELEM
#define NW   5
#define NTHR 320          // NW*64

// workspace layout (bytes)
#define OBS_OFF 0
#define ANY_OFF  524288   // B_SZ*T_SZ
#define WHH_OFF  526336   // +2048
#define WIH_OFF  679936   // +153600   (wih: 30720 bytes) total 710656

typedef float f32x4_t __attribute__((ext_vector_type(4)));
typedef short bf16x8_t __attribute__((ext_vector_type(8)));

__device__ __forceinline__ unsigned short f2bf(float x) {
  unsigned int u = __float_as_uint(x);
  unsigned int r = ((u >> 16) & 1u) + 0x7FFFu;
  return (unsigned short)((u + r) >> 16);
}
__device__ __forceinline__ float sigm_f(float v) {
  return 1.f / (1.f + __expf(-v));
}
__device__ __forceinline__ float tanh_f(float v) {
  float a = fabsf(v);
  float e = __expf(-2.f * a);
  float m = (1.f - e) / (1.f + e);
  return copysignf(m, v);
}

// ---------------- phase 0: zero any-flags ----------------
__global__ void k_zero(unsigned* __restrict__ anyv) {
  int i = blockIdx.x * blockDim.x + threadIdx.x;
  if (i < T_SZ) anyv[i] = 0u;
}

// ---------------- phase 1: obs[b][t] + any_obs[t] ----------------
__global__ __launch_bounds__(256) void k_obs(const float* __restrict__ X,
                                             unsigned char* __restrict__ obs,
                                             unsigned* __restrict__ anyv) {
  const int b = blockIdx.x;
  const float* Xb = X + (size_t)b * T_SZ * C_CH;
  for (int t = threadIdx.x; t < T_SZ; t += blockDim.x) {
    const float* cur = Xb + t * C_CH;
    const float* prv = cur - C_CH;
    float m = -1e30f;
    if (t == 0) {
      #pragma unroll
      for (int c = 1; c <= 32; ++c) m = fmaxf(m, cur[c]);
    } else {
      #pragma unroll
      for (int c = 1; c <= 32; ++c) m = fmaxf(m, cur[c] - prv[c]);
    }
    unsigned char o = (m > 0.5f) ? (unsigned char)1 : (unsigned char)0;
    obs[(size_t)b * T_SZ + t] = o;
    if (o) atomicOr(&anyv[t], 1u);
  }
}

// ---------------- phase 1b: pack weights into bf16 MFMA B-fragments -------
// whh frag element (q,g,kt,lane,j) = w_hh[g*160 + q*16 + (lane&15)][kt*32 + (lane>>4)*8 + j]
// wih frag element (q,g,lane,j)    = w_ih[g*160 + q*16 + (lane&15)][(lane>>4)*8 + j]
__global__ __launch_bounds__(256) void k_pack(const float* __restrict__ w_ih,
                                              const float* __restrict__ w_hh,
                                              unsigned short* __restrict__ whh_f,
                                              unsigned short* __restrict__ wih_f) {
  int i = blockIdx.x * 256 + threadIdx.x;
  if (i < 9600) {
    int l = i & 63; int kt = (i >> 6) % 5; int g = (i / 320) % 3; int q = i / 960;
    int row = g * 160 + q * 16 + (l & 15);
    const float* src = w_hh + (size_t)row * HID + kt * 32 + (l >> 4) * 8;
    unsigned short* dst = whh_f + (size_t)i * 8;
    #pragma unroll
    for (int j = 0; j < 8; ++j) dst[j] = f2bf(src[j]);
  } else if (i < 11520) {
    int i2 = i - 9600;
    int l = i2 & 63; int g = (i2 >> 6) % 3; int q = i2 / 192;
    int row = g * 160 + q * 16 + (l & 15);
    const float* src = w_ih + (size_t)row * 32 + (l >> 4) * 8;
    unsigned short* dst = wih_f + (size_t)i2 * 8;
    #pragma unroll
    for (int j = 0; j < 8; ++j) dst[j] = f2bf(src[j]);
  }
}

// ---------------- phase 2: batched MFMA recurrence ------------------------
// 8 batch elements per block, 5 waves. Wave w owns col-bundles q = w and w+5
// (16 h-columns each, all 3 gates). Weight B-frags resident in VGPRs.
// h broadcast via double-buffered bf16 A-frag LDS; gates combined in-register.
__global__ __launch_bounds__(NTHR, 1) void k_scan(
    const float* __restrict__ times, const float* __restrict__ X,
    const int* __restrict__ fidx,
    const float* __restrict__ b_ih, const float* __restrict__ b_hh,
    const float* __restrict__ lin_w, const float* __restrict__ lin_b,
    const unsigned char* __restrict__ obs, const unsigned* __restrict__ anyv,
    const unsigned short* __restrict__ whh_f, const unsigned short* __restrict__ wih_f,
    float* __restrict__ out)
{
  const int b0 = blockIdx.x * M_ELEM;
  const int tid = threadIdx.x;
  const int wid = tid >> 6;
  const int lane = tid & 63;

  __shared__ __align__(16) unsigned short afrag[2][5][64][8]; // h A-frags dbuf
  __shared__ __align__(16) float xbuf[2][M_ELEM][36];          // x-piece dbuf (pad 36)
  __shared__ float x0buf[2][M_ELEM];
  __shared__ unsigned char obsbuf[2][M_ELEM];
  __shared__ int anybuf[2];
  __shared__ float dtv[2][M_ELEM];
  __shared__ float times_lds[T_SZ];
  __shared__ __align__(16) float hm[M_ELEM][HID];

  // ---- init ----
  for (int i = tid; i < T_SZ; i += NTHR) times_lds[i] = times[i];
  { unsigned int* az = (unsigned int*)afrag;
    for (int i = tid; i < 2560; i += NTHR) az[i] = 0u; }
  if (tid < M_ELEM) { dtv[0][tid] = 0.f; dtv[1][tid] = 0.f; }

  int maxfi = 0;
  #pragma unroll
  for (int e = 0; e < M_ELEM; ++e) maxfi = max(maxfi, fidx[b0 + e]);
  int fi_r[4];
  #pragma unroll
  for (int r = 0; r < 4; ++r) fi_r[r] = fidx[b0 + (((lane >> 4) & 1) * 4 + r)];
  const int fi_e = fidx[b0 + (tid & 7)];

  // ---- resident weight fragments ----
  bf16x8_t whh_v[2][3][5];
  bf16x8_t wih_v[2][3];
  float b_r[2], b_z[2], b_ni[2], b_nh[2];
  int base_i[2];
  #pragma unroll
  for (int bq = 0; bq < 2; ++bq) {
    const int q = wid + 5 * bq;
    #pragma unroll
    for (int g = 0; g < 3; ++g) {
      #pragma unroll
      for (int kt = 0; kt < 5; ++kt)
        whh_v[bq][g][kt] = *(const bf16x8_t*)(whh_f + ((size_t)((q * 3 + g) * 5 + kt) * 64 + lane) * 8);
      wih_v[bq][g] = *(const bf16x8_t*)(wih_f + ((size_t)(q * 3 + g) * 64 + lane) * 8);
    }
    const int col = q * 16 + (lane & 15);
    b_r[bq]  = b_ih[col] + b_hh[col];
    b_z[bq]  = b_ih[160 + col] + b_hh[160 + col];
    b_ni[bq] = b_ih[320 + col];
    b_nh[bq] = b_hh[320 + col];
    const int kt = col >> 5, kk = col & 31;
    base_i[bq] = (kt * 64 + (kk >> 3) * 16) * 8 + (kk & 7);
  }
  f32x4_t h_reg[2] = {{0.f,0.f,0.f,0.f},{0.f,0.f,0.f,0.f}};
  const f32x4_t z4 = {0.f,0.f,0.f,0.f};

  // ---- stage t=0 into parity 0 ----
  if (tid < 256) {
    int e = tid >> 5, c = tid & 31;
    xbuf[0][e][c] = X[(size_t)(b0 + e) * T_SZ * C_CH + 33 + c];
  } else if (tid < 264) {
    x0buf[0][tid - 256] = X[(size_t)(b0 + tid - 256) * T_SZ * C_CH];
  } else if (tid < 272) {
    obsbuf[0][tid - 264] = obs[(size_t)(b0 + tid - 264) * T_SZ];
  } else if (tid == 272) {
    anybuf[0] = (int)anyv[0];
  }
  __syncthreads();

  // ---- the recurrence ----
  for (int t = 0; t <= maxfi; ++t) {
    const int p = t & 1, pn = p ^ 1;

    // prefetch step t+1 into registers (latency hides under MFMA+combine)
    const int tn = (t < maxfi) ? (t + 1) : maxfi;
    float vnext = 0.f; unsigned char onext = 0; int anext = 0;
    if (tid < 256) {
      vnext = X[(size_t)(b0 + (tid >> 5)) * T_SZ * C_CH + (size_t)tn * C_CH + 33 + (tid & 31)];
    } else if (tid < 264) {
      vnext = X[(size_t)(b0 + tid - 256) * T_SZ * C_CH + (size_t)tn * C_CH];
    } else if (tid < 272) {
      onext = obs[(size_t)(b0 + tid - 264) * T_SZ + tn];
    } else if (tid == 272) {
      anext = (int)anyv[tn];
    }

    const int anyB = anybuf[p];

    if (anyB) {
      // x A-frag: row m=lane&15 (real if <8), k = (lane>>4)*8 + j; k==0 gets +dt
      const int mrow = lane & 15;
      const int k0 = (lane >> 4) * 8;
      const float* xr = &xbuf[p][mrow & 7][k0];
      float4 xa = *(const float4*)(xr);
      float4 xb = *(const float4*)(xr + 4);
      if (lane < 16) xa.x += dtv[p][mrow & 7];
      bf16x8_t xf;
      xf[0]=(short)f2bf(xa.x); xf[1]=(short)f2bf(xa.y); xf[2]=(short)f2bf(xa.z); xf[3]=(short)f2bf(xa.w);
      xf[4]=(short)f2bf(xb.x); xf[5]=(short)f2bf(xb.y); xf[6]=(short)f2bf(xb.z); xf[7]=(short)f2bf(xb.w);

      // h A-frags (written last step into afrag[p])
      bf16x8_t hf[5];
      #pragma unroll
      for (int kt = 0; kt < 5; ++kt)
        hf[kt] = *(const bf16x8_t*)&afrag[p][kt][lane][0];

      int ob[4];
      #pragma unroll
      for (int r = 0; r < 4; ++r) ob[r] = (int)obsbuf[p][((lane >> 4) & 1) * 4 + r];

      unsigned short* apn = &afrag[pn][0][0][0];

      #pragma unroll
      for (int bq = 0; bq < 2; ++bq) {
        f32x4_t accr  = __builtin_amdgcn_mfma_f32_16x16x32_bf16(xf, wih_v[bq][0], z4, 0, 0, 0);
        f32x4_t accz  = __builtin_amdgcn_mfma_f32_16x16x32_bf16(xf, wih_v[bq][1], z4, 0, 0, 0);
        f32x4_t accni = __builtin_amdgcn_mfma_f32_16x16x32_bf16(xf, wih_v[bq][2], z4, 0, 0, 0);
        f32x4_t accnh = z4;
        #pragma unroll
        for (int kt = 0; kt < 5; ++kt) {
          accr  = __builtin_amdgcn_mfma_f32_16x16x32_bf16(hf[kt], whh_v[bq][0][kt], accr,  0, 0, 0);
          accz  = __builtin_amdgcn_mfma_f32_16x16x32_bf16(hf[kt], whh_v[bq][1][kt], accz,  0, 0, 0);
          accnh = __builtin_amdgcn_mfma_f32_16x16x32_bf16(hf[kt], whh_v[bq][2][kt], accnh, 0, 0, 0);
        }
        if (lane < 32) {
          #pragma unroll
          for (int r = 0; r < 4; ++r) {
            const int m = (lane >> 4) * 4 + r;
            float rr = sigm_f(accr[r] + b_r[bq]);
            float zz = sigm_f(accz[r] + b_z[bq]);
            float nn = tanh_f(accni[r] + b_ni[bq] + rr * (accnh[r] + b_nh[bq]));
            float ho = h_reg[bq][r];
            float hnew = (ob[r] && t <= fi_r[r]) ? (nn + zz * (ho - nn)) : ho;
            h_reg[bq][r] = hnew;
            apn[base_i[bq] + m * 8] = f2bf(hnew);
          }
        }
      }
    } else {
      // no element in the whole batch observes: h unchanged; carry frags over
      const unsigned int* s = (const unsigned int*)afrag[p];
      unsigned int* d = (unsigned int*)afrag[pn];
      for (int i = tid; i < 1280; i += NTHR) d[i] = s[i];
    }

    // dt carry (double-buffered; delta only when anyB && !obs && alive)
    if (tid < 8) {
      float del = 0.f;
      if (anyB && !obsbuf[p][tid] && t <= fi_e)
        del = x0buf[p][tid] - times_lds[(t == 0) ? 0 : (t - 1)];
      dtv[pn][tid] = dtv[p][tid] + del;
    }

    // publish staged step t+1
    if (tid < 256) {
      xbuf[pn][tid >> 5][tid & 31] = vnext;
    } else if (tid < 264) {
      x0buf[pn][tid - 256] = vnext;
    } else if (tid < 272) {
      obsbuf[pn][tid - 264] = onext;
    } else if (tid == 272) {
      anybuf[pn] = anext;
    }
    __syncthreads();
  }

  // ---- epilogue: h -> LDS, then out = lin_w @ h + lin_b ----
  if (lane < 32) {
    #pragma unroll
    for (int bq = 0; bq < 2; ++bq) {
      const int col = (wid + 5 * bq) * 16 + (lane & 15);
      #pragma unroll
      for (int r = 0; r < 4; ++r)
        hm[(lane >> 4) * 4 + r][col] = h_reg[bq][r];
    }
  }
  __syncthreads();
  if (tid < 256) {
    const int e = tid >> 5, o = tid & 31;
    const float4* lw = (const float4*)(lin_w + o * HID);
    const float4* hv = (const float4*)(&hm[e][0]);
    float a0 = 0.f, a1 = 0.f, a2 = 0.f, a3 = 0.f;
    #pragma unroll
    for (int k = 0; k < HID / 4; ++k) {
      float4 w = lw[k], h = hv[k];
      a0 = fmaf(w.x, h.x, a0); a1 = fmaf(w.y, h.y, a1);
      a2 = fmaf(w.z, h.z, a2); a3 = fmaf(w.w, h.w, a3);
    }
    out[(size_t)(b0 + e) * OUTD + o] = lin_b[o] + (a0 + a1) + (a2 + a3);
  }
}

extern "C" void kernel_launch(void* const* d_in, const int* in_sizes, int n_in,
                              void* d_out, int out_size, void* d_ws, size_t ws_size,
                              hipStream_t stream) {
  const float* times = (const float*)d_in[0];
  const float* X     = (const float*)d_in[1];
  const int*   fidx  = (const int*)d_in[2];
  const float* w_ih  = (const float*)d_in[3];
  const float* w_hh  = (const float*)d_in[4];
  const float* b_ih  = (const float*)d_in[5];
  const float* b_hh  = (const float*)d_in[6];
  const float* lin_w = (const float*)d_in[7];
  const float* lin_b = (const float*)d_in[8];
  float* outp = (float*)d_out;

  unsigned char* obsb = (unsigned char*)d_ws + OBS_OFF;
  unsigned* anyv = (unsigned*)((char*)d_ws + ANY_OFF);
  unsigned short* whh_f = (unsigned short*)((char*)d_ws + WHH_OFF);
  unsigned short* wih_f = (unsigned short*)((char*)d_ws + WIH_OFF);

  k_zero<<<1, 512, 0, stream>>>(anyv);
  k_obs<<<B_SZ, 256, 0, stream>>>(X, obsb, anyv);
  k_pack<<<45, 256, 0, stream>>>(w_ih, w_hh, whh_f, wih_f);
  k_scan<<<NBLK, NTHR, 0, stream>>>(times, X, fidx, b_ih, b_hh, lin_w, lin_b,
                                    obsb, anyv, whh_f, wih_f, outp);
}

// Round 5
// 1106.728 us; speedup vs baseline: 14.7473x; 1.3187x over previous
//
#include <hip/hip_runtime.h>
#include <math.h>

#define B_SZ 1024
#define T_SZ 512
#define C_CH 65
#define HID  160
#define OUTD 32
#define M_ELEM 8
#define NBLK 128          // B_SZ / M_ELEM
#define NW   10
#define NTHR 640          // NW*64

// workspace layout (bytes)
#define OBS_OFF 0
#define ANY_OFF  524288   // B_SZ*T_SZ
#define WHH_OFF  526336   // +2048
#define WIH_OFF  679936   // +153600 (wih: 30720) total 710656

typedef float f32x4_t __attribute__((ext_vector_type(4)));
typedef short bf16x8_t __attribute__((ext_vector_type(8)));

__device__ __forceinline__ unsigned short f2bf(float x) {
  unsigned int u = __float_as_uint(x);
  unsigned int r = ((u >> 16) & 1u) + 0x7FFFu;
  return (unsigned short)((u + r) >> 16);
}
__device__ __forceinline__ float sigm_f(float v) {
  return 1.f / (1.f + __expf(-v));
}
__device__ __forceinline__ float tanh_f(float v) {
  float a = fabsf(v);
  float e = __expf(-2.f * a);
  float m = (1.f - e) / (1.f + e);
  return copysignf(m, v);
}

// ---------------- phase 0: zero any-flags ----------------
__global__ void k_zero(unsigned* __restrict__ anyv) {
  int i = blockIdx.x * blockDim.x + threadIdx.x;
  if (i < T_SZ) anyv[i] = 0u;
}

// ---------------- phase 1: obs[b][t] + any_obs[t] ----------------
__global__ __launch_bounds__(256) void k_obs(const float* __restrict__ X,
                                             unsigned char* __restrict__ obs,
                                             unsigned* __restrict__ anyv) {
  const int b = blockIdx.x;
  const float* Xb = X + (size_t)b * T_SZ * C_CH;
  for (int t = threadIdx.x; t < T_SZ; t += blockDim.x) {
    const float* cur = Xb + t * C_CH;
    const float* prv = cur - C_CH;
    float m = -1e30f;
    if (t == 0) {
      #pragma unroll
      for (int c = 1; c <= 32; ++c) m = fmaxf(m, cur[c]);
    } else {
      #pragma unroll
      for (int c = 1; c <= 32; ++c) m = fmaxf(m, cur[c] - prv[c]);
    }
    unsigned char o = (m > 0.5f) ? (unsigned char)1 : (unsigned char)0;
    obs[(size_t)b * T_SZ + t] = o;
    if (o) atomicOr(&anyv[t], 1u);
  }
}

// ---------------- phase 1b: pack weights into bf16 MFMA B-fragments -------
// whh frag (q,g,kt,lane,j) = w_hh[g*160 + q*16 + (lane&15)][kt*32 + (lane>>4)*8 + j]
// wih frag (q,g,lane,j)    = w_ih[g*160 + q*16 + (lane&15)][(lane>>4)*8 + j]
__global__ __launch_bounds__(256) void k_pack(const float* __restrict__ w_ih,
                                              const float* __restrict__ w_hh,
                                              unsigned short* __restrict__ whh_f,
                                              unsigned short* __restrict__ wih_f) {
  int i = blockIdx.x * 256 + threadIdx.x;
  if (i < 9600) {
    int l = i & 63; int kt = (i >> 6) % 5; int g = (i / 320) % 3; int q = i / 960;
    int row = g * 160 + q * 16 + (l & 15);
    const float* src = w_hh + (size_t)row * HID + kt * 32 + (l >> 4) * 8;
    unsigned short* dst = whh_f + (size_t)i * 8;
    #pragma unroll
    for (int j = 0; j < 8; ++j) dst[j] = f2bf(src[j]);
  } else if (i < 11520) {
    int i2 = i - 9600;
    int l = i2 & 63; int g = (i2 >> 6) % 3; int q = i2 / 192;
    int row = g * 160 + q * 16 + (l & 15);
    const float* src = w_ih + (size_t)row * 32 + (l >> 4) * 8;
    unsigned short* dst = wih_f + (size_t)i2 * 8;
    #pragma unroll
    for (int j = 0; j < 8; ++j) dst[j] = f2bf(src[j]);
  }
}

// ---------------- phase 2: batched MFMA recurrence ------------------------
// 8 batch elements per block, 10 waves; wave w owns col-bundle q=w (16 cols,
// all 3 gates, 18 MFMAs/step). Weight frags resident per wave (72 VGPRs).
// X A-frag rows loaded global->reg one step ahead; +dt folded out of bf16
// into an fp32 rank-1 correction (dt * w_ih[:,0]) in the combine.
__global__ __launch_bounds__(NTHR, 1) void k_scan(
    const float* __restrict__ times, const float* __restrict__ X,
    const int* __restrict__ fidx,
    const float* __restrict__ w_ih,
    const float* __restrict__ b_ih, const float* __restrict__ b_hh,
    const float* __restrict__ lin_w, const float* __restrict__ lin_b,
    const unsigned char* __restrict__ obs, const unsigned* __restrict__ anyv,
    const unsigned short* __restrict__ whh_f, const unsigned short* __restrict__ wih_f,
    float* __restrict__ out)
{
  const int b0 = blockIdx.x * M_ELEM;
  const int tid = threadIdx.x;
  const int wid = tid >> 6;
  const int lane = tid & 63;
  const int q = wid;

  __shared__ __align__(16) unsigned short afrag[2][5][64][8]; // h A-frags dbuf
  __shared__ unsigned char obsbuf[2][M_ELEM];
  __shared__ int anybuf[2];
  __shared__ float dtv[2][M_ELEM];
  __shared__ float times_lds[T_SZ];
  __shared__ __align__(16) float hm[M_ELEM][HID];

  // ---- init ----
  for (int i = tid; i < T_SZ; i += NTHR) times_lds[i] = times[i];
  { unsigned int* az = (unsigned int*)afrag;
    for (int i = tid; i < 2560; i += NTHR) az[i] = 0u; }
  if (tid < M_ELEM) dtv[0][tid] = 0.f;

  int maxfi = 0;
  #pragma unroll
  for (int e = 0; e < M_ELEM; ++e) maxfi = max(maxfi, fidx[b0 + e]);
  int fi_r[4];
  #pragma unroll
  for (int r = 0; r < 4; ++r) fi_r[r] = fidx[b0 + (((lane >> 4) & 1) * 4 + r)];
  const int fi_e = (tid < M_ELEM) ? fidx[b0 + tid] : 0;

  // ---- resident weight fragments (one bundle per wave) ----
  bf16x8_t whh_v[3][5];
  bf16x8_t wih_v[3];
  #pragma unroll
  for (int g = 0; g < 3; ++g) {
    #pragma unroll
    for (int kt = 0; kt < 5; ++kt)
      whh_v[g][kt] = *(const bf16x8_t*)(whh_f + ((size_t)((q * 3 + g) * 5 + kt) * 64 + lane) * 8);
    wih_v[g] = *(const bf16x8_t*)(wih_f + ((size_t)(q * 3 + g) * 64 + lane) * 8);
  }
  const int col = q * 16 + (lane & 15);
  const float b_r  = b_ih[col] + b_hh[col];
  const float b_z  = b_ih[160 + col] + b_hh[160 + col];
  const float b_ni = b_ih[320 + col];
  const float b_nh = b_hh[320 + col];
  const float w0r = w_ih[(size_t)col * 32];
  const float w0z = w_ih[(size_t)(160 + col) * 32];
  const float w0n = w_ih[(size_t)(320 + col) * 32];
  const int base_u16 = ((col >> 5) * 64 + ((col & 31) >> 3) * 16) * 8 + (col & 7);

  f32x4_t h_reg = {0.f, 0.f, 0.f, 0.f};
  const f32x4_t z4 = {0.f, 0.f, 0.f, 0.f};

  // per-lane X source: A-frag row m=lane&15 (m&7 = element), k0=(lane>>4)*8
  const float* xrow_base =
      X + ((size_t)(b0 + ((lane & 15) & 7)) * T_SZ) * C_CH + 33 + ((lane >> 4) * 8);

  // ---- prologue: load t=0 into registers / parity 0 ----
  float xc[8];
  #pragma unroll
  for (int j = 0; j < 8; ++j) xc[j] = xrow_base[j];
  float x0c = 0.f;
  if (tid < M_ELEM) {
    x0c = X[((size_t)(b0 + tid) * T_SZ) * C_CH];
    obsbuf[0][tid] = obs[(size_t)(b0 + tid) * T_SZ];
  }
  if (tid == M_ELEM) anybuf[0] = (int)anyv[0];
  __syncthreads();

  // ---- the recurrence ----
  for (int t = 0; t <= maxfi; ++t) {
    const int p = t & 1, pn = p ^ 1;
    const int tn = (t < maxfi) ? (t + 1) : maxfi;

    // prefetch step t+1 (global->reg; hides under this step's compute)
    float xn[8];
    const float* xr = xrow_base + (size_t)tn * C_CH;
    #pragma unroll
    for (int j = 0; j < 8; ++j) xn[j] = xr[j];
    float x0n = 0.f; unsigned char on = 0; int an = 0;
    if (tid < M_ELEM) {
      x0n = X[((size_t)(b0 + tid) * T_SZ + tn) * C_CH];
      on  = obs[(size_t)(b0 + tid) * T_SZ + tn];
    }
    if (tid == M_ELEM) an = (int)anyv[tn];

    // current x A-frag (bf16)
    bf16x8_t xf;
    #pragma unroll
    for (int j = 0; j < 8; ++j) xf[j] = (short)f2bf(xc[j]);

    // h A-frags (written last step into afrag[p])
    bf16x8_t hfv[5];
    #pragma unroll
    for (int kt = 0; kt < 5; ++kt)
      hfv[kt] = *(const bf16x8_t*)&afrag[p][kt][lane][0];

    // 18 MFMAs: r = ih+5hh, z = ih+5hh, ni = ih, nh = 5hh
    f32x4_t accr  = __builtin_amdgcn_mfma_f32_16x16x32_bf16(xf, wih_v[0], z4, 0, 0, 0);
    f32x4_t accz  = __builtin_amdgcn_mfma_f32_16x16x32_bf16(xf, wih_v[1], z4, 0, 0, 0);
    f32x4_t accni = __builtin_amdgcn_mfma_f32_16x16x32_bf16(xf, wih_v[2], z4, 0, 0, 0);
    f32x4_t accnh = z4;
    #pragma unroll
    for (int kt = 0; kt < 5; ++kt) {
      accr  = __builtin_amdgcn_mfma_f32_16x16x32_bf16(hfv[kt], whh_v[0][kt], accr,  0, 0, 0);
      accz  = __builtin_amdgcn_mfma_f32_16x16x32_bf16(hfv[kt], whh_v[1][kt], accz,  0, 0, 0);
      accnh = __builtin_amdgcn_mfma_f32_16x16x32_bf16(hfv[kt], whh_v[2][kt], accnh, 0, 0, 0);
    }

    // combine (real rows live in lanes<32), rank-1 dt correction in fp32
    if (lane < 32) {
      unsigned short* apn = &afrag[pn][0][0][0];
      #pragma unroll
      for (int r = 0; r < 4; ++r) {
        const int m = ((lane >> 4) & 1) * 4 + r;
        const float dtm = dtv[p][m];
        const int ob = (int)obsbuf[p][m];
        float rr = sigm_f(accr[r] + b_r + dtm * w0r);
        float zz = sigm_f(accz[r] + b_z + dtm * w0z);
        float nn = tanh_f(accni[r] + b_ni + dtm * w0n + rr * (accnh[r] + b_nh));
        float ho = h_reg[r];
        float hnew = (ob && t <= fi_r[r]) ? (nn + zz * (ho - nn)) : ho;
        h_reg[r] = hnew;
        apn[base_u16 + m * 8] = f2bf(hnew);
      }
    }

    // dt carry + publish staged flags (wave 0 only)
    if (tid < M_ELEM) {
      float del = 0.f;
      if (anybuf[p] && !obsbuf[p][tid] && t <= fi_e)
        del = x0c - times_lds[(t == 0) ? 0 : (t - 1)];
      dtv[pn][tid] = dtv[p][tid] + del;
      obsbuf[pn][tid] = on;
    }
    if (tid == M_ELEM) anybuf[pn] = an;

    #pragma unroll
    for (int j = 0; j < 8; ++j) xc[j] = xn[j];
    x0c = x0n;
    __syncthreads();
  }

  // ---- epilogue: h -> LDS, then out = lin_w @ h + lin_b ----
  if (lane < 32) {
    #pragma unroll
    for (int r = 0; r < 4; ++r)
      hm[((lane >> 4) & 1) * 4 + r][col] = h_reg[r];
  }
  __syncthreads();
  if (tid < 256) {
    const int e = tid >> 5, o = tid & 31;
    const float4* lw = (const float4*)(lin_w + o * HID);
    const float4* hv = (const float4*)(&hm[e][0]);
    float a0 = 0.f, a1 = 0.f, a2 = 0.f, a3 = 0.f;
    #pragma unroll
    for (int k = 0; k < HID / 4; ++k) {
      float4 w = lw[k], h = hv[k];
      a0 = fmaf(w.x, h.x, a0); a1 = fmaf(w.y, h.y, a1);
      a2 = fmaf(w.z, h.z, a2); a3 = fmaf(w.w, h.w, a3);
    }
    out[(size_t)(b0 + e) * OUTD + o] = lin_b[o] + (a0 + a1) + (a2 + a3);
  }
}

extern "C" void kernel_launch(void* const* d_in, const int* in_sizes, int n_in,
                              void* d_out, int out_size, void* d_ws, size_t ws_size,
                              hipStream_t stream) {
  const float* times = (const float*)d_in[0];
  const float* X     = (const float*)d_in[1];
  const int*   fidx  = (const int*)d_in[2];
  const float* w_ih  = (const float*)d_in[3];
  const float* w_hh  = (const float*)d_in[4];
  const float* b_ih  = (const float*)d_in[5];
  const float* b_hh  = (const float*)d_in[6];
  const float* lin_w = (const float*)d_in[7];
  const float* lin_b = (const float*)d_in[8];
  float* outp = (float*)d_out;

  unsigned char* obsb = (unsigned char*)d_ws + OBS_OFF;
  unsigned* anyv = (unsigned*)((char*)d_ws + ANY_OFF);
  unsigned short* whh_f = (unsigned short*)((char*)d_ws + WHH_OFF);
  unsigned short* wih_f = (unsigned short*)((char*)d_ws + WIH_OFF);

  k_zero<<<1, 512, 0, stream>>>(anyv);
  k_obs<<<B_SZ, 256, 0, stream>>>(X, obsb, anyv);
  k_pack<<<45, 256, 0, stream>>>(w_ih, w_hh, whh_f, wih_f);
  k_scan<<<NBLK, NTHR, 0, stream>>>(times, X, fidx, w_ih, b_ih, b_hh,
                                    lin_w, lin_b, obsb, anyv, whh_f, wih_f, outp);
}

// Round 6
// 1105.660 us; speedup vs baseline: 14.7615x; 1.0010x over previous
//
#include <hip/hip_runtime.h>
#include <math.h>

#define B_SZ 1024
#define T_SZ 512
#define C_CH 65
#define HID  160
#define OUTD 32
#define M_ELEM 8
#define NBLK 128          // B_SZ / M_ELEM
#define NW   10
#define NTHR 640          // NW*64

// workspace layout (bytes)
#define OBS_OFF 0
#define ANY_OFF  524288   // B_SZ*T_SZ
#define WHH_OFF  526336   // +2048
#define WIH_OFF  679936   // +153600 (wih: 30720) total 710656

typedef float f32x4_t __attribute__((ext_vector_type(4)));
typedef short bf16x8_t __attribute__((ext_vector_type(8)));

__device__ __forceinline__ unsigned short f2bf(float x) {
  unsigned int u = __float_as_uint(x);
  unsigned int r = ((u >> 16) & 1u) + 0x7FFFu;
  return (unsigned short)((u + r) >> 16);
}
__device__ __forceinline__ float sigm_f(float v) {
  return 1.f / (1.f + __expf(-v));
}
__device__ __forceinline__ float tanh_f(float v) {
  float a = fabsf(v);
  float e = __expf(-2.f * a);
  float m = (1.f - e) / (1.f + e);
  return copysignf(m, v);
}

// ---------------- phase 0: zero any-flags ----------------
__global__ void k_zero(unsigned* __restrict__ anyv) {
  int i = blockIdx.x * blockDim.x + threadIdx.x;
  if (i < T_SZ) anyv[i] = 0u;
}

// ---------------- phase 1: obs[b][t] + any_obs[t] ----------------
__global__ __launch_bounds__(256) void k_obs(const float* __restrict__ X,
                                             unsigned char* __restrict__ obs,
                                             unsigned* __restrict__ anyv) {
  const int b = blockIdx.x;
  const float* Xb = X + (size_t)b * T_SZ * C_CH;
  for (int t = threadIdx.x; t < T_SZ; t += blockDim.x) {
    const float* cur = Xb + t * C_CH;
    const float* prv = cur - C_CH;
    float m = -1e30f;
    if (t == 0) {
      #pragma unroll
      for (int c = 1; c <= 32; ++c) m = fmaxf(m, cur[c]);
    } else {
      #pragma unroll
      for (int c = 1; c <= 32; ++c) m = fmaxf(m, cur[c] - prv[c]);
    }
    unsigned char o = (m > 0.5f) ? (unsigned char)1 : (unsigned char)0;
    obs[(size_t)b * T_SZ + t] = o;
    if (o) atomicOr(&anyv[t], 1u);
  }
}

// ---------------- phase 1b: pack weights into bf16 MFMA B-fragments -------
// whh frag (q,g,kt,lane,j) = w_hh[g*160 + q*16 + (lane&15)][kt*32 + (lane>>4)*8 + j]
// wih frag (q,g,lane,j)    = w_ih[g*160 + q*16 + (lane&15)][(lane>>4)*8 + j]
__global__ __launch_bounds__(256) void k_pack(const float* __restrict__ w_ih,
                                              const float* __restrict__ w_hh,
                                              unsigned short* __restrict__ whh_f,
                                              unsigned short* __restrict__ wih_f) {
  int i = blockIdx.x * 256 + threadIdx.x;
  if (i < 9600) {
    int l = i & 63; int kt = (i >> 6) % 5; int g = (i / 320) % 3; int q = i / 960;
    int row = g * 160 + q * 16 + (l & 15);
    const float* src = w_hh + (size_t)row * HID + kt * 32 + (l >> 4) * 8;
    unsigned short* dst = whh_f + (size_t)i * 8;
    #pragma unroll
    for (int j = 0; j < 8; ++j) dst[j] = f2bf(src[j]);
  } else if (i < 11520) {
    int i2 = i - 9600;
    int l = i2 & 63; int g = (i2 >> 6) % 3; int q = i2 / 192;
    int row = g * 160 + q * 16 + (l & 15);
    const float* src = w_ih + (size_t)row * 32 + (l >> 4) * 8;
    unsigned short* dst = wih_f + (size_t)i2 * 8;
    #pragma unroll
    for (int j = 0; j < 8; ++j) dst[j] = f2bf(src[j]);
  }
}

// ---------------- phase 2: batched MFMA recurrence ------------------------
// 8 batch elements per block, 10 waves; wave w owns col-bundle q=w (16 cols,
// all 3 gates, 18 MFMAs/step). Weight frags resident per wave (72 VGPRs).
// X A-frag rows loaded global->reg one step ahead; +dt folded out of bf16
// into an fp32 rank-1 correction (dt * w_ih[:,0]) in the combine.
__global__ __launch_bounds__(NTHR, 1) void k_scan(
    const float* __restrict__ times, const float* __restrict__ X,
    const int* __restrict__ fidx,
    const float* __restrict__ w_ih,
    const float* __restrict__ b_ih, const float* __restrict__ b_hh,
    const float* __restrict__ lin_w, const float* __restrict__ lin_b,
    const unsigned char* __restrict__ obs, const unsigned* __restrict__ anyv,
    const unsigned short* __restrict__ whh_f, const unsigned short* __restrict__ wih_f,
    float* __restrict__ out)
{
  const int b0 = blockIdx.x * M_ELEM;
  const int tid = threadIdx.x;
  const int wid = tid >> 6;
  const int lane = tid & 63;
  const int q = wid;

  __shared__ __align__(16) unsigned short afrag[2][5][64][8]; // h A-frags dbuf
  __shared__ unsigned char obsbuf[2][M_ELEM];
  __shared__ int anybuf[2];
  __shared__ float dtv[2][M_ELEM];
  __shared__ float times_lds[T_SZ];
  __shared__ __align__(16) float hm[M_ELEM][HID];

  // ---- init ----
  for (int i = tid; i < T_SZ; i += NTHR) times_lds[i] = times[i];
  { unsigned int* az = (unsigned int*)afrag;
    for (int i = tid; i < 2560; i += NTHR) az[i] = 0u; }
  if (tid < M_ELEM) dtv[0][tid] = 0.f;

  int maxfi = 0;
  #pragma unroll
  for (int e = 0; e < M_ELEM; ++e) maxfi = max(maxfi, fidx[b0 + e]);
  int fi_r[4];
  #pragma unroll
  for (int r = 0; r < 4; ++r) fi_r[r] = fidx[b0 + (((lane >> 4) & 1) * 4 + r)];
  const int fi_e = (tid < M_ELEM) ? fidx[b0 + tid] : 0;

  // ---- resident weight fragments (one bundle per wave) ----
  bf16x8_t whh_v[3][5];
  bf16x8_t wih_v[3];
  #pragma unroll
  for (int g = 0; g < 3; ++g) {
    #pragma unroll
    for (int kt = 0; kt < 5; ++kt)
      whh_v[g][kt] = *(const bf16x8_t*)(whh_f + ((size_t)((q * 3 + g) * 5 + kt) * 64 + lane) * 8);
    wih_v[g] = *(const bf16x8_t*)(wih_f + ((size_t)(q * 3 + g) * 64 + lane) * 8);
  }
  const int col = q * 16 + (lane & 15);
  const float b_r  = b_ih[col] + b_hh[col];
  const float b_z  = b_ih[160 + col] + b_hh[160 + col];
  const float b_ni = b_ih[320 + col];
  const float b_nh = b_hh[320 + col];
  const float w0r = w_ih[(size_t)col * 32];
  const float w0z = w_ih[(size_t)(160 + col) * 32];
  const float w0n = w_ih[(size_t)(320 + col) * 32];
  const int base_u16 = ((col >> 5) * 64 + ((col & 31) >> 3) * 16) * 8 + (col & 7);

  f32x4_t h_reg = {0.f, 0.f, 0.f, 0.f};
  const f32x4_t z4 = {0.f, 0.f, 0.f, 0.f};

  // per-lane X source: A-frag row m=lane&15 (m&7 = element), k0=(lane>>4)*8
  const float* xrow_base =
      X + ((size_t)(b0 + ((lane & 15) & 7)) * T_SZ) * C_CH + 33 + ((lane >> 4) * 8);

  // ---- prologue: load t=0 into registers / parity 0 ----
  float xc[8];
  #pragma unroll
  for (int j = 0; j < 8; ++j) xc[j] = xrow_base[j];
  float x0c = 0.f;
  if (tid < M_ELEM) {
    x0c = X[((size_t)(b0 + tid) * T_SZ) * C_CH];
    obsbuf[0][tid] = obs[(size_t)(b0 + tid) * T_SZ];
  }
  if (tid == M_ELEM) anybuf[0] = (int)anyv[0];
  __syncthreads();

  // ---- the recurrence ----
  for (int t = 0; t <= maxfi; ++t) {
    const int p = t & 1, pn = p ^ 1;
    const int tn = (t < maxfi) ? (t + 1) : maxfi;

    // prefetch step t+1 (global->reg; hides under this step's compute)
    float xn[8];
    const float* xr = xrow_base + (size_t)tn * C_CH;
    #pragma unroll
    for (int j = 0; j < 8; ++j) xn[j] = xr[j];
    float x0n = 0.f; unsigned char on = 0; int an = 0;
    if (tid < M_ELEM) {
      x0n = X[((size_t)(b0 + tid) * T_SZ + tn) * C_CH];
      on  = obs[(size_t)(b0 + tid) * T_SZ + tn];
    }
    if (tid == M_ELEM) an = (int)anyv[tn];

    // current x A-frag (bf16)
    bf16x8_t xf;
    #pragma unroll
    for (int j = 0; j < 8; ++j) xf[j] = (short)f2bf(xc[j]);

    // h A-frags (written last step into afrag[p])
    bf16x8_t hfv[5];
    #pragma unroll
    for (int kt = 0; kt < 5; ++kt)
      hfv[kt] = *(const bf16x8_t*)&afrag[p][kt][lane][0];

    // 18 MFMAs: r = ih+5hh, z = ih+5hh, ni = ih, nh = 5hh
    f32x4_t accr  = __builtin_amdgcn_mfma_f32_16x16x32_bf16(xf, wih_v[0], z4, 0, 0, 0);
    f32x4_t accz  = __builtin_amdgcn_mfma_f32_16x16x32_bf16(xf, wih_v[1], z4, 0, 0, 0);
    f32x4_t accni = __builtin_amdgcn_mfma_f32_16x16x32_bf16(xf, wih_v[2], z4, 0, 0, 0);
    f32x4_t accnh = z4;
    #pragma unroll
    for (int kt = 0; kt < 5; ++kt) {
      accr  = __builtin_amdgcn_mfma_f32_16x16x32_bf16(hfv[kt], whh_v[0][kt], accr,  0, 0, 0);
      accz  = __builtin_amdgcn_mfma_f32_16x16x32_bf16(hfv[kt], whh_v[1][kt], accz,  0, 0, 0);
      accnh = __builtin_amdgcn_mfma_f32_16x16x32_bf16(hfv[kt], whh_v[2][kt], accnh, 0, 0, 0);
    }

    // combine (real rows live in lanes<32), rank-1 dt correction in fp32
    if (lane < 32) {
      unsigned short* apn = &afrag[pn][0][0][0];
      #pragma unroll
      for (int r = 0; r < 4; ++r) {
        const int m = ((lane >> 4) & 1) * 4 + r;
        const float dtm = dtv[p][m];
        const int ob = (int)obsbuf[p][m];
        float rr = sigm_f(accr[r] + b_r + dtm * w0r);
        float zz = sigm_f(accz[r] + b_z + dtm * w0z);
        float nn = tanh_f(accni[r] + b_ni + dtm * w0n + rr * (accnh[r] + b_nh));
        float ho = h_reg[r];
        float hnew = (ob && t <= fi_r[r]) ? (nn + zz * (ho - nn)) : ho;
        h_reg[r] = hnew;
        apn[base_u16 + m * 8] = f2bf(hnew);
      }
    }

    // dt carry + publish staged flags (wave 0 only)
    if (tid < M_ELEM) {
      float del = 0.f;
      if (anybuf[p] && !obsbuf[p][tid] && t <= fi_e)
        del = x0c - times_lds[(t == 0) ? 0 : (t - 1)];
      dtv[pn][tid] = dtv[p][tid] + del;
      obsbuf[pn][tid] = on;
    }
    if (tid == M_ELEM) anybuf[pn] = an;

    #pragma unroll
    for (int j = 0; j < 8; ++j) xc[j] = xn[j];
    x0c = x0n;
    __syncthreads();
  }

  // ---- epilogue: h -> LDS, then out = lin_w @ h + lin_b ----
  if (lane < 32) {
    #pragma unroll
    for (int r = 0; r < 4; ++r)
      hm[((lane >> 4) & 1) * 4 + r][col] = h_reg[r];
  }
  __syncthreads();
  if (tid < 256) {
    const int e = tid >> 5, o = tid & 31;
    const float4* lw = (const float4*)(lin_w + o * HID);
    const float4* hv = (const float4*)(&hm[e][0]);
    float a0 = 0.f, a1 = 0.f, a2 = 0.f, a3 = 0.f;
    #pragma unroll
    for (int k = 0; k < HID / 4; ++k) {
      float4 w = lw[k], h = hv[k];
      a0 = fmaf(w.x, h.x, a0); a1 = fmaf(w.y, h.y, a1);
      a2 = fmaf(w.z, h.z, a2); a3 = fmaf(w.w, h.w, a3);
    }
    out[(size_t)(b0 + e) * OUTD + o] = lin_b[o] + (a0 + a1) + (a2 + a3);
  }
}

extern "C" void kernel_launch(void* const* d_in, const int* in_sizes, int n_in,
                              void* d_out, int out_size, void* d_ws, size_t ws_size,
                              hipStream_t stream) {
  const float* times = (const float*)d_in[0];
  const float* X     = (const float*)d_in[1];
  const int*   fidx  = (const int*)d_in[2];
  const float* w_ih  = (const float*)d_in[3];
  const float* w_hh  = (const float*)d_in[4];
  const float* b_ih  = (const float*)d_in[5];
  const float* b_hh  = (const float*)d_in[6];
  const float* lin_w = (const float*)d_in[7];
  const float* lin_b = (const float*)d_in[8];
  float* outp = (float*)d_out;

  unsigned char* obsb = (unsigned char*)d_ws + OBS_OFF;
  unsigned* anyv = (unsigned*)((char*)d_ws + ANY_OFF);
  unsigned short* whh_f = (unsigned short*)((char*)d_ws + WHH_OFF);
  unsigned short* wih_f = (unsigned short*)((char*)d_ws + WIH_OFF);

  k_zero<<<1, 512, 0, stream>>>(anyv);
  k_obs<<<B_SZ, 256, 0, stream>>>(X, obsb, anyv);
  k_pack<<<45, 256, 0, stream>>>(w_ih, w_hh, whh_f, wih_f);
  k_scan<<<NBLK, NTHR, 0, stream>>>(times, X, fidx, w_ih, b_ih, b_hh,
                                    lin_w, lin_b, obsb, anyv, whh_f, wih_f, outp);
}

// Round 7
// 742.363 us; speedup vs baseline: 21.9855x; 1.4894x over previous
//
#include <hip/hip_runtime.h>
#include <math.h>

#define B_SZ 1024
#define T_SZ 512
#define C_CH 65
#define HID  160
#define OUTD 32
#define M_ELEM 8
#define NBLK 128          // B_SZ / M_ELEM
#define NW   10
#define NTHR 640          // NW*64

// workspace layout (bytes)
#define OBS_OFF 0
#define ANY_OFF  524288   // B_SZ*T_SZ
#define WHH_OFF  526336   // +2048
#define WIH_OFF  679936   // +153600 (wih: 30720) total 710656

typedef float f32x4_t __attribute__((ext_vector_type(4)));
typedef short bf16x8_t __attribute__((ext_vector_type(8)));

__device__ __forceinline__ unsigned short f2bf(float x) {
  unsigned int u = __float_as_uint(x);
  unsigned int r = ((u >> 16) & 1u) + 0x7FFFu;
  return (unsigned short)((u + r) >> 16);
}
// packed f32x2 -> bf16x2 (RNE), single VOP3 (T12 / m214-verified on gfx950)
__device__ __forceinline__ unsigned cvt_pk_bf16(float lo, float hi) {
  unsigned r;
  asm("v_cvt_pk_bf16_f32 %0, %1, %2" : "=v"(r) : "v"(lo), "v"(hi));
  return r;
}
__device__ __forceinline__ float sigm_f(float v) {
  return 1.f / (1.f + __expf(-v));
}
__device__ __forceinline__ float tanh_f(float v) {
  float a = fabsf(v);
  float e = __expf(-2.f * a);
  float m = (1.f - e) / (1.f + e);
  return copysignf(m, v);
}

// ---------------- phase 0: zero any-flags ----------------
__global__ void k_zero(unsigned* __restrict__ anyv) {
  int i = blockIdx.x * blockDim.x + threadIdx.x;
  if (i < T_SZ) anyv[i] = 0u;
}

// ---------------- phase 1: obs[b][t] + any_obs[t] ----------------
__global__ __launch_bounds__(256) void k_obs(const float* __restrict__ X,
                                             unsigned char* __restrict__ obs,
                                             unsigned* __restrict__ anyv) {
  const int b = blockIdx.x;
  const float* Xb = X + (size_t)b * T_SZ * C_CH;
  for (int t = threadIdx.x; t < T_SZ; t += blockDim.x) {
    const float* cur = Xb + t * C_CH;
    const float* prv = cur - C_CH;
    float m = -1e30f;
    if (t == 0) {
      #pragma unroll
      for (int c = 1; c <= 32; ++c) m = fmaxf(m, cur[c]);
    } else {
      #pragma unroll
      for (int c = 1; c <= 32; ++c) m = fmaxf(m, cur[c] - prv[c]);
    }
    unsigned char o = (m > 0.5f) ? (unsigned char)1 : (unsigned char)0;
    obs[(size_t)b * T_SZ + t] = o;
    if (o) atomicOr(&anyv[t], 1u);
  }
}

// ---------------- phase 1b: pack weights into bf16 MFMA B-fragments -------
__global__ __launch_bounds__(256) void k_pack(const float* __restrict__ w_ih,
                                              const float* __restrict__ w_hh,
                                              unsigned short* __restrict__ whh_f,
                                              unsigned short* __restrict__ wih_f) {
  int i = blockIdx.x * 256 + threadIdx.x;
  if (i < 9600) {
    int l = i & 63; int kt = (i >> 6) % 5; int g = (i / 320) % 3; int q = i / 960;
    int row = g * 160 + q * 16 + (l & 15);
    const float* src = w_hh + (size_t)row * HID + kt * 32 + (l >> 4) * 8;
    unsigned short* dst = whh_f + (size_t)i * 8;
    #pragma unroll
    for (int j = 0; j < 8; ++j) dst[j] = f2bf(src[j]);
  } else if (i < 11520) {
    int i2 = i - 9600;
    int l = i2 & 63; int g = (i2 >> 6) % 3; int q = i2 / 192;
    int row = g * 160 + q * 16 + (l & 15);
    const float* src = w_ih + (size_t)row * 32 + (l >> 4) * 8;
    unsigned short* dst = wih_f + (size_t)i2 * 8;
    #pragma unroll
    for (int j = 0; j < 8; ++j) dst[j] = f2bf(src[j]);
  }
}

// ---------------- phase 2: batched MFMA recurrence ------------------------
// 8 elements/block, 10 waves, wave q owns 16 gate-cols x 3 gates (18 MFMA).
// A-frag rows 8-15 duplicate rows 0-7 (x: lane&7 source; h: broadcast read
// at lane&55) so ALL 64 lanes combine 2 rows each (halved VALU/trans).
__global__ __launch_bounds__(NTHR, 1) void k_scan(
    const float* __restrict__ times, const float* __restrict__ X,
    const int* __restrict__ fidx,
    const float* __restrict__ w_ih,
    const float* __restrict__ b_ih, const float* __restrict__ b_hh,
    const float* __restrict__ lin_w, const float* __restrict__ lin_b,
    const unsigned char* __restrict__ obs, const unsigned* __restrict__ anyv,
    const unsigned short* __restrict__ whh_f, const unsigned short* __restrict__ wih_f,
    float* __restrict__ out)
{
  const int b0 = blockIdx.x * M_ELEM;
  const int tid = threadIdx.x;
  const int wid = tid >> 6;
  const int lane = tid & 63;
  const int q = wid;

  __shared__ __align__(16) unsigned short afrag[2][5][64][8]; // h A-frags dbuf
  __shared__ float2 dtobs[2][M_ELEM];                         // {dt, obs} per elem
  __shared__ int anybuf[2];
  __shared__ float times_lds[T_SZ];
  __shared__ __align__(16) float hm[M_ELEM][HID];

  // ---- init ----
  for (int i = tid; i < T_SZ; i += NTHR) times_lds[i] = times[i];
  { unsigned int* az = (unsigned int*)afrag;
    for (int i = tid; i < 2560; i += NTHR) az[i] = 0u; }

  int maxfi = 0;
  #pragma unroll
  for (int e = 0; e < M_ELEM; ++e) maxfi = max(maxfi, fidx[b0 + e]);

  // this lane's two combine rows (valid for ALL 64 lanes via row duplication)
  const int mA = ((lane >> 4) & 1) * 4 + ((lane >> 5) & 1) * 2;
  const int mB = mA + 1;
  const int fiA = fidx[b0 + mA];
  const int fiB = fidx[b0 + mB];
  const int fi_e = (tid < M_ELEM) ? fidx[b0 + tid] : 0;

  // ---- resident weight fragments (one col-bundle per wave) ----
  bf16x8_t whh_v[3][5];
  bf16x8_t wih_v[3];
  #pragma unroll
  for (int g = 0; g < 3; ++g) {
    #pragma unroll
    for (int kt = 0; kt < 5; ++kt)
      whh_v[g][kt] = *(const bf16x8_t*)(whh_f + ((size_t)((q * 3 + g) * 5 + kt) * 64 + lane) * 8);
    wih_v[g] = *(const bf16x8_t*)(wih_f + ((size_t)(q * 3 + g) * 64 + lane) * 8);
  }
  const int col = q * 16 + (lane & 15);
  const float b_r  = b_ih[col] + b_hh[col];
  const float b_z  = b_ih[160 + col] + b_hh[160 + col];
  const float b_ni = b_ih[320 + col];
  const float b_nh = b_hh[320 + col];
  const float w0r = w_ih[(size_t)col * 32];
  const float w0z = w_ih[(size_t)(160 + col) * 32];
  const float w0n = w_ih[(size_t)(320 + col) * 32];
  const int base_u16 = ((col >> 5) * 64 + ((col & 31) >> 3) * 16) * 8 + (col & 7);

  float hA = 0.f, hB = 0.f;
  const f32x4_t z4 = {0.f, 0.f, 0.f, 0.f};

  // per-lane X source: row duplication via lane&7
  const float* xrow_base =
      X + ((size_t)(b0 + (lane & 7)) * T_SZ) * C_CH + 33 + ((lane >> 4) * 8);
  // h-frag broadcast read address (rows 8-15 read rows 0-7's slot)
  const int lread = (lane & 48) | (lane & 7);

  // ---- prologue: t=0 ----
  float xc[8];
  #pragma unroll
  for (int j = 0; j < 8; ++j) xc[j] = xrow_base[j];
  float x0c = 0.f;
  if (tid < M_ELEM) {
    x0c = X[((size_t)(b0 + tid) * T_SZ) * C_CH];
    dtobs[0][tid] = make_float2(0.f, obs[(size_t)(b0 + tid) * T_SZ] ? 1.f : 0.f);
  }
  if (tid == M_ELEM) anybuf[0] = (int)anyv[0];
  __syncthreads();

  // ---- the recurrence ----
  for (int t = 0; t <= maxfi; ++t) {
    const int p = t & 1, pn = p ^ 1;
    const int tn = (t < maxfi) ? (t + 1) : maxfi;

    // A. prefetch t+1 (global->reg; hides under this step)
    float xn[8];
    const float* xr = xrow_base + (size_t)tn * C_CH;
    #pragma unroll
    for (int j = 0; j < 8; ++j) xn[j] = xr[j];
    float x0n = 0.f, onf = 0.f; int an = 0;
    if (tid < M_ELEM) {
      x0n = X[((size_t)(b0 + tid) * T_SZ + tn) * C_CH];
      onf = obs[(size_t)(b0 + tid) * T_SZ + tn] ? 1.f : 0.f;
    }
    if (tid == M_ELEM) an = (int)anyv[tn];

    // B. per-row state (broadcast LDS b64 reads)
    const float2 doA = dtobs[p][mA];
    const float2 doB = dtobs[p][mB];

    // C. h A-frags
    bf16x8_t hfv[5];
    #pragma unroll
    for (int kt = 0; kt < 5; ++kt)
      hfv[kt] = *(const bf16x8_t*)&afrag[p][kt][lread][0];

    // D. x A-frag (4 packed converts)
    bf16x8_t xf;
    unsigned* xfu = (unsigned*)&xf;
    #pragma unroll
    for (int j = 0; j < 4; ++j) xfu[j] = cvt_pk_bf16(xc[2 * j], xc[2 * j + 1]);

    // E. 18 MFMAs
    f32x4_t accr  = __builtin_amdgcn_mfma_f32_16x16x32_bf16(xf, wih_v[0], z4, 0, 0, 0);
    f32x4_t accz  = __builtin_amdgcn_mfma_f32_16x16x32_bf16(xf, wih_v[1], z4, 0, 0, 0);
    f32x4_t accni = __builtin_amdgcn_mfma_f32_16x16x32_bf16(xf, wih_v[2], z4, 0, 0, 0);
    f32x4_t accnh = z4;
    #pragma unroll
    for (int kt = 0; kt < 5; ++kt) {
      accr  = __builtin_amdgcn_mfma_f32_16x16x32_bf16(hfv[kt], whh_v[0][kt], accr,  0, 0, 0);
      accz  = __builtin_amdgcn_mfma_f32_16x16x32_bf16(hfv[kt], whh_v[1][kt], accz,  0, 0, 0);
      accnh = __builtin_amdgcn_mfma_f32_16x16x32_bf16(hfv[kt], whh_v[2][kt], accnh, 0, 0, 0);
    }

    // F. row select: lower lanes take regs {0,1} (rows mA,mB), upper {2,3}
    const bool up = (lane >= 32);
    const float vrA = up ? accr[2]  : accr[0],  vrB = up ? accr[3]  : accr[1];
    const float vzA = up ? accz[2]  : accz[0],  vzB = up ? accz[3]  : accz[1];
    const float viA = up ? accni[2] : accni[0], viB = up ? accni[3] : accni[1];
    const float vhA = up ? accnh[2] : accnh[0], vhB = up ? accnh[3] : accnh[1];

    // G. combine (2 rows per lane), fp32 rank-1 dt correction
    {
      const float dtm = doA.x;
      float rr = sigm_f(vrA + b_r + dtm * w0r);
      float zz = sigm_f(vzA + b_z + dtm * w0z);
      float nn = tanh_f(viA + b_ni + dtm * w0n + rr * (vhA + b_nh));
      float upd = nn + zz * (hA - nn);
      hA = (doA.y != 0.f && t <= fiA) ? upd : hA;
    }
    {
      const float dtm = doB.x;
      float rr = sigm_f(vrB + b_r + dtm * w0r);
      float zz = sigm_f(vzB + b_z + dtm * w0z);
      float nn = tanh_f(viB + b_ni + dtm * w0n + rr * (vhB + b_nh));
      float upd = nn + zz * (hB - nn);
      hB = (doB.y != 0.f && t <= fiB) ? upd : hB;
    }
    {
      const unsigned hw = cvt_pk_bf16(hA, hB);
      unsigned short* apn = &afrag[pn][0][0][0];
      apn[base_u16 + mA * 8] = (unsigned short)hw;
      apn[base_u16 + mB * 8] = (unsigned short)(hw >> 16);
    }

    // H. dt/obs carry (wave 0) + any carry
    if (tid < M_ELEM) {
      float2 cur = dtobs[p][tid];
      float del = (anybuf[p] && cur.y == 0.f && t <= fi_e)
                  ? (x0c - times_lds[(t == 0) ? 0 : (t - 1)]) : 0.f;
      dtobs[pn][tid] = make_float2(cur.x + del, onf);
    }
    if (tid == M_ELEM) anybuf[pn] = an;

    // I. roll prefetch regs
    #pragma unroll
    for (int j = 0; j < 8; ++j) xc[j] = xn[j];
    x0c = x0n;
    __syncthreads();
  }

  // ---- epilogue: h -> LDS, then out = lin_w @ h + lin_b ----
  hm[mA][col] = hA;
  hm[mB][col] = hB;
  __syncthreads();
  if (tid < 256) {
    const int e = tid >> 5, o = tid & 31;
    const float4* lw = (const float4*)(lin_w + o * HID);
    const float4* hv = (const float4*)(&hm[e][0]);
    float a0 = 0.f, a1 = 0.f, a2 = 0.f, a3 = 0.f;
    #pragma unroll
    for (int k = 0; k < HID / 4; ++k) {
      float4 w = lw[k], h = hv[k];
      a0 = fmaf(w.x, h.x, a0); a1 = fmaf(w.y, h.y, a1);
      a2 = fmaf(w.z, h.z, a2); a3 = fmaf(w.w, h.w, a3);
    }
    out[(size_t)(b0 + e) * OUTD + o] = lin_b[o] + (a0 + a1) + (a2 + a3);
  }
}

extern "C" void kernel_launch(void* const* d_in, const int* in_sizes, int n_in,
                              void* d_out, int out_size, void* d_ws, size_t ws_size,
                              hipStream_t stream) {
  const float* times = (const float*)d_in[0];
  const float* X     = (const float*)d_in[1];
  const int*   fidx  = (const int*)d_in[2];
  const float* w_ih  = (const float*)d_in[3];
  const float* w_hh  = (const float*)d_in[4];
  const float* b_ih  = (const float*)d_in[5];
  const float* b_hh  = (const float*)d_in[6];
  const float* lin_w = (const float*)d_in[7];
  const float* lin_b = (const float*)d_in[8];
  float* outp = (float*)d_out;

  unsigned char* obsb = (unsigned char*)d_ws + OBS_OFF;
  unsigned* anyv = (unsigned*)((char*)d_ws + ANY_OFF);
  unsigned short* whh_f = (unsigned short*)((char*)d_ws + WHH_OFF);
  unsigned short* wih_f = (unsigned short*)((char*)d_ws + WIH_OFF);

  k_zero<<<1, 512, 0, stream>>>(anyv);
  k_obs<<<B_SZ, 256, 0, stream>>>(X, obsb, anyv);
  k_pack<<<45, 256, 0, stream>>>(w_ih, w_hh, whh_f, wih_f);
  k_scan<<<NBLK, NTHR, 0, stream>>>(times, X, fidx, w_ih, b_ih, b_hh,
                                    lin_w, lin_b, obsb, anyv, whh_f, wih_f, outp);
}